// Round 3
// baseline (4608.477 us; speedup 1.0000x reference)
//
#include <hip/hip_runtime.h>
#include <math.h>

#define DIMN 20
#define DD 21
#define NN 2048
#define MCN 32
#define UNITS 128
#define SIGC 0.2f
#define MUC 0.05f
#define RC 0.05f
#define DELTAC 0.01f

#define TM 32
#define PTOT (NN + MCN*NN + NN)
#define NBLK (PTOT/TM)

// ws layout (floats)
#define OFF_L 0
#define OFF_WT 512
#define OFF_U4 (OFF_WT + 4*16384)        // 66048 : packed [Uz|Ug|Ur|Uh] 21x512
#define OFF_W3 (OFF_U4 + DD*512)         // 76800 : packed [Wz|Wg|Wr] 128x384
#define OFF_FP1 (OFF_W3 + UNITS*384)     // 125952
#define OFF_VAL1 (OFF_FP1 + NN*DD)
#define OFF_VAL2 (OFF_VAL1 + NN)
#define OFF_T12  (OFF_VAL2 + NN)
#define OFF_GATES (OFF_T12 + NN)         // layer-2 gate stash: NBLK * 16384 floats
#define GB_STRIDE 16384

// LDS layout (floats): S0|S1|S2|Db|xT|Vb = 17728 floats = 70,912 B -> 2 blocks/CU
#define L_S0 0
#define L_S1 4096
#define L_S2 8192
#define L_D  12288
#define L_XT 16384
#define L_VB (16384 + 672)
#define L_TOT (16384 + 672 + 672)

#define ELT44(...) _Pragma("unroll") for (int p = 0; p < 4; p++){ _Pragma("unroll") for (int jj = 0; jj < 4; jj++){ __VA_ARGS__; } }

__device__ __forceinline__ int offq(int row, int p0){
    return row*32 + ((p0 + 4*(row&7)) & 31);
}
__device__ __forceinline__ int offs(int row, int p){
    return row*32 + (((p & 28) + 4*(row&7)) & 31) + (p & 3);
}

#define FMA16(acc, s4, w4) \
  acc[0][0]=fmaf(s4.x,w4.x,acc[0][0]); acc[0][1]=fmaf(s4.x,w4.y,acc[0][1]); \
  acc[0][2]=fmaf(s4.x,w4.z,acc[0][2]); acc[0][3]=fmaf(s4.x,w4.w,acc[0][3]); \
  acc[1][0]=fmaf(s4.y,w4.x,acc[1][0]); acc[1][1]=fmaf(s4.y,w4.y,acc[1][1]); \
  acc[1][2]=fmaf(s4.y,w4.z,acc[1][2]); acc[1][3]=fmaf(s4.y,w4.w,acc[1][3]); \
  acc[2][0]=fmaf(s4.z,w4.x,acc[2][0]); acc[2][1]=fmaf(s4.z,w4.y,acc[2][1]); \
  acc[2][2]=fmaf(s4.z,w4.z,acc[2][2]); acc[2][3]=fmaf(s4.z,w4.w,acc[2][3]); \
  acc[3][0]=fmaf(s4.w,w4.x,acc[3][0]); acc[3][1]=fmaf(s4.w,w4.y,acc[3][1]); \
  acc[3][2]=fmaf(s4.w,w4.z,acc[3][2]); acc[3][3]=fmaf(s4.w,w4.w,acc[3][3]);

// acc += vec[k][p] * W[k][j]; W direct from global (L1/L2), 2-row lookahead.
__device__ __forceinline__ void mm_g(const float* __restrict__ gW, int K,
    const float* __restrict__ vec, float acc[4][4], int jg, int p0)
{
    const float* wp = gW + 4*jg;
    int kp = K & ~1;
    float4 wa0 = *(const float4*)(wp);
    float4 sa0 = *(const float4*)(vec + offq(0, p0));
    float4 wa1 = *(const float4*)(wp + UNITS);
    float4 sa1 = *(const float4*)(vec + offq(1, p0));
    for (int c = 0; c < kp; c += 2){
        float4 wb0, wb1, sb0, sb1;
        bool more = (c + 2) < kp;
        if (more){
            wb0 = *(const float4*)(wp + (c+2)*UNITS);
            sb0 = *(const float4*)(vec + offq(c+2, p0));
            wb1 = *(const float4*)(wp + (c+3)*UNITS);
            sb1 = *(const float4*)(vec + offq(c+3, p0));
        }
        FMA16(acc, sa0, wa0)
        FMA16(acc, sa1, wa1)
        if (more){ wa0=wb0; wa1=wb1; sa0=sb0; sa1=sb1; }
    }
    if (K & 1){
        float4 w4 = *(const float4*)(wp + kp*UNITS);
        float4 s4 = *(const float4*)(vec + offq(kp, p0));
        FMA16(acc, s4, w4)
    }
}

// fused z,g,r: W3 rows of 384; 2-row lookahead (K even = 128)
__device__ __forceinline__ void mm3_g(const float* __restrict__ gW, int K,
    const float* __restrict__ vec, float a0[4][4], float a1[4][4], float a2[4][4],
    int jg, int p0)
{
    const float* wp = gW + 4*jg;
    int kp = K & ~1;
    float4 u0 = *(const float4*)(wp);
    float4 u1 = *(const float4*)(wp + 128);
    float4 u2 = *(const float4*)(wp + 256);
    float4 x0 = *(const float4*)(wp + 384);
    float4 x1 = *(const float4*)(wp + 384 + 128);
    float4 x2 = *(const float4*)(wp + 384 + 256);
    float4 s0 = *(const float4*)(vec + offq(0, p0));
    float4 s1 = *(const float4*)(vec + offq(1, p0));
    for (int c = 0; c < kp; c += 2){
        float4 nu0,nu1,nu2,nx0,nx1,nx2,ns0,ns1;
        bool more = (c + 2) < kp;
        if (more){
            const float* r0 = wp + (c+2)*384;
            const float* r1 = wp + (c+3)*384;
            nu0 = *(const float4*)(r0); nu1 = *(const float4*)(r0+128); nu2 = *(const float4*)(r0+256);
            nx0 = *(const float4*)(r1); nx1 = *(const float4*)(r1+128); nx2 = *(const float4*)(r1+256);
            ns0 = *(const float4*)(vec + offq(c+2, p0));
            ns1 = *(const float4*)(vec + offq(c+3, p0));
        }
        FMA16(a0, s0, u0) FMA16(a1, s0, u1) FMA16(a2, s0, u2)
        FMA16(a0, s1, x0) FMA16(a1, s1, x1) FMA16(a2, s1, x2)
        if (more){ u0=nu0;u1=nu1;u2=nu2;x0=nx0;x1=nx1;x2=nx2;s0=ns0;s1=ns1; }
    }
    if (K & 1){
        const float* r = wp + kp*384;
        float4 s4 = *(const float4*)(vec + offq(kp, p0));
        float4 w0 = *(const float4*)(r);
        float4 w1v = *(const float4*)(r + 128);
        float4 w2 = *(const float4*)(r + 256);
        FMA16(a0, s4, w0) FMA16(a1, s4, w1v) FMA16(a2, s4, w2)
    }
}

// fused U-pass for all 4 gates: U4 rows of 512; 1-row lookahead (K=21 small)
__device__ __forceinline__ void mm4_g(const float* __restrict__ gW, int K,
    const float* __restrict__ vec, float a0[4][4], float a1[4][4], float a2[4][4], float a3[4][4],
    int jg, int p0)
{
    const float* wp = gW + 4*jg;
    float4 w0 = *(const float4*)(wp);
    float4 w1v = *(const float4*)(wp + 128);
    float4 w2 = *(const float4*)(wp + 256);
    float4 w3 = *(const float4*)(wp + 384);
    float4 s4 = *(const float4*)(vec + offq(0, p0));
    for (int k = 0; k < K; k++){
        float4 n0,n1,n2,n3,ns;
        bool more = (k + 1) < K;
        if (more){
            const float* r = wp + (k+1)*512;
            n0 = *(const float4*)(r);
            n1 = *(const float4*)(r + 128);
            n2 = *(const float4*)(r + 256);
            n3 = *(const float4*)(r + 384);
            ns = *(const float4*)(vec + offq(k+1, p0));
        }
        FMA16(a0, s4, w0) FMA16(a1, s4, w1v) FMA16(a2, s4, w2) FMA16(a3, s4, w3)
        if (more){ w0=n0; w1v=n1; w2=n2; w3=n3; s4=ns; }
    }
}

__device__ __forceinline__ void write_own(float* buf, const float v[4][4], int j0, int p0){
    #pragma unroll
    for (int jj = 0; jj < 4; jj++){
        int j = j0 + jj;
        float4 q = make_float4(v[0][jj], v[1][jj], v[2][jj], v[3][jj]);
        *(float4*)(buf + offq(j, p0)) = q;
    }
}
__device__ __forceinline__ void read_own(const float* buf, float v[4][4], int j0, int p0){
    #pragma unroll
    for (int jj = 0; jj < 4; jj++){
        int j = j0 + jj;
        float4 q = *(const float4*)(buf + offq(j, p0));
        v[0][jj]=q.x; v[1][jj]=q.y; v[2][jj]=q.z; v[3][jj]=q.w;
    }
}

__global__ void chol_kernel(float* __restrict__ Lout)
{
    if (threadIdx.x == 0 && blockIdx.x == 0) {
        double Lc[DIMN][DIMN];
        for (int i = 0; i < DIMN; i++)
            for (int j = 0; j <= i; j++) {
                double s = 0.01 * (0.5 + (i == j ? 0.5 : 0.0));
                for (int t2 = 0; t2 < j; t2++) s -= Lc[i][t2] * Lc[j][t2];
                Lc[i][j] = (i == j) ? sqrt(s) : s / Lc[j][j];
            }
        for (int i = 0; i < DIMN; i++)
            for (int j = 0; j < DIMN; j++)
                Lout[i*DIMN + j] = (j <= i) ? (float)Lc[i][j] : 0.0f;
    }
}

__global__ void transpose_k(const float* __restrict__ wz, const float* __restrict__ wg,
                            const float* __restrict__ wr, const float* __restrict__ wh,
                            float* __restrict__ WT)
{
    int idx = blockIdx.x*256 + threadIdx.x;           // 0..65535
    int q = idx >> 14, r2 = idx & 16383, k = r2 >> 7, j = r2 & 127;
    const float* src = (q==0)? wz : (q==1)? wg : (q==2)? wr : wh;
    WT[(q<<14) + j*UNITS + k] = src[k*UNITS + j];
}

// pack U4 = [uz|ug|ur|uh] 21x512 and W3 = [wz|wg|wr] 128x384
__global__ void pack_u4w3(const float* __restrict__ uz, const float* __restrict__ ug,
                          const float* __restrict__ ur, const float* __restrict__ uh,
                          const float* __restrict__ wz, const float* __restrict__ wg,
                          const float* __restrict__ wr,
                          float* __restrict__ U4, float* __restrict__ W3)
{
    int idx = blockIdx.x*256 + threadIdx.x;
    if (idx < 128*384){
        int k = idx/384, c = idx - k*384, g = c >> 7, j = c & 127;
        const float* s = (g==0)? wz : (g==1)? wg : wr;
        W3[idx] = s[k*UNITS + j];
        return;
    }
    int i2 = idx - 128*384;
    if (i2 < 21*512){
        int k = i2/512, c = i2 - k*512, g = c >> 7, j = c & 127;
        const float* s = (g==0)? uz : (g==1)? ug : (g==2)? ur : uh;
        U4[i2] = s[k*UNITS + j];
    }
}

#define DGM_PARAMS \
    const float* __restrict__ inputs, const float* __restrict__ eps, \
    const float* __restrict__ w1, const float* __restrict__ b1, \
    const float* __restrict__ uz, const float* __restrict__ bz, \
    const float* __restrict__ ug, const float* __restrict__ bg, \
    const float* __restrict__ ur, const float* __restrict__ br, \
    const float* __restrict__ uh, const float* __restrict__ wh, const float* __restrict__ bh, \
    const float* __restrict__ wv, const float* __restrict__ bv, \
    const float* __restrict__ Lm, const float* __restrict__ WT, \
    const float* __restrict__ U4, const float* __restrict__ W3, \
    float* __restrict__ gws, \
    float* __restrict__ fp1, float* __restrict__ val1, float* __restrict__ val2, \
    float* __restrict__ t12acc

#define DGM_ARGS inputs, eps, w1, b1, uz, bz, ug, bg, ur, br, uh, wh, bh, wv, bv, \
    Lm, WT, U4, W3, gws, fp1, val1, val2, t12acc

template<int SG>
__device__ __forceinline__ void dgm_body(float* lds, DGM_PARAMS)
{
    float* S0 = lds + L_S0;
    float* S1 = lds + L_S1;
    float* S2 = lds + L_S2;
    float* Db = lds + L_D;
    float* xT = lds + L_XT;
    float* Vb = lds + L_VB;

    const int t  = threadIdx.x;
    const int jg = t & 31;
    const int pg = t >> 5;
    const int p0 = pg * 4;
    const int j0 = jg * 4;
    const int P0 = blockIdx.x * TM;
    const int type = (P0 < NN) ? 0 : (P0 < NN + MCN*NN) ? 1 : 2;
    int base_n = 0, mrow = 0;
    if (type == 1){ int q = P0 - NN; mrow = q >> 11; base_n = q & (NN-1); }

    float* gb = gws + (size_t)blockIdx.x * GB_STRIDE;

    // ---- build x tile (and violation V for type 1) ----
    {
        int p = t & 31, kq = t >> 5;
        for (int ki = 0; ki < 3; ki++){
            int k = kq + 8*ki;
            if (k > DIMN) break;
            float xv;
            if (type == 0){
                xv = inputs[(P0 + p)*DD + k];
            } else if (type == 2){
                xv = inputs[(NN + (P0 - NN - MCN*NN) + p)*DD + k];
            } else {
                int n = base_n + p;
                float x1v = inputs[n*DD + k];
                if (k == DIMN) xv = x1v;
                else {
                    const float* ep = eps + (size_t)(mrow*NN + n)*DIMN;
                    float a = x1v;
                    for (int d = 0; d < DIMN; d++) a = fmaf(ep[d], Lm[k*DIMN + d], a);
                    float viol = a * (SIGC * x1v);
                    Vb[offs(k, p)] = viol;
                    xv = x1v + viol;
                }
            }
            xT[offs(k, p)] = xv;
        }
    }
    __syncthreads();

    // ---- forward ----
    float s_own[4][4];
    {
        float acc[4][4];
        float4 b = *(const float4*)(b1 + j0);
        #pragma unroll
        for (int p = 0; p < 4; p++){ acc[p][0]=b.x; acc[p][1]=b.y; acc[p][2]=b.z; acc[p][3]=b.w; }
        mm_g(w1, DD, xT, acc, jg, p0);
        ELT44(s_own[p][jj] = tanhf(acc[p][jj]))
        write_own(S0, s_own, j0, p0);
        __syncthreads();
    }

    float zt[4][4], gt[4][4], rt[4][4], ht[4][4];

#define GATES(SIN, SMUL) \
    { \
    float4 q0 = *(const float4*)(bz + j0), q1 = *(const float4*)(bg + j0); \
    float4 q2 = *(const float4*)(br + j0), q3 = *(const float4*)(bh + j0); \
    float az[4][4], ag[4][4], ar[4][4], ah[4][4]; \
    _Pragma("unroll") for (int p = 0; p < 4; p++){ \
        az[p][0]=q0.x; az[p][1]=q0.y; az[p][2]=q0.z; az[p][3]=q0.w; \
        ag[p][0]=q1.x; ag[p][1]=q1.y; ag[p][2]=q1.z; ag[p][3]=q1.w; \
        ar[p][0]=q2.x; ar[p][1]=q2.y; ar[p][2]=q2.z; ar[p][3]=q2.w; \
        ah[p][0]=q3.x; ah[p][1]=q3.y; ah[p][2]=q3.z; ah[p][3]=q3.w; } \
    mm4_g(U4, DD, xT, az, ag, ar, ah, jg, p0); \
    mm3_g(W3, UNITS, SIN, az, ag, ar, jg, p0); \
    ELT44(zt[p][jj]=tanhf(az[p][jj]); gt[p][jj]=tanhf(ag[p][jj]); rt[p][jj]=tanhf(ar[p][jj])) \
    { float tt[4][4]; ELT44(tt[p][jj] = SMUL[p][jj]*rt[p][jj]) \
      __syncthreads(); write_own(Db, tt, j0, p0); __syncthreads(); } \
    mm_g(wh, UNITS, Db, ah, jg, p0); \
    ELT44(ht[p][jj] = tanhf(ah[p][jj])) \
    }

#define FWD_LAYER(SIN) \
    GATES(SIN, s_own) \
    ELT44(s_own[p][jj] = (1.f - gt[p][jj])*ht[p][jj] + zt[p][jj]*s_own[p][jj])

    FWD_LAYER(S0)                      // layer 1
    write_own(S1, s_own, j0, p0);
    __syncthreads();
    FWD_LAYER(S1)                      // layer 2 -- stash gates for backward
    if (SG && type != 2){
        write_own(gb,         zt, j0, p0);
        write_own(gb + 4096,  gt, j0, p0);
        write_own(gb + 8192,  rt, j0, p0);
        write_own(gb + 12288, ht, j0, p0);
    }
    write_own(S2, s_own, j0, p0);
    __syncthreads();
    FWD_LAYER(S2)                      // layer 3 -- zt/gt/rt/ht live into backward

    // ---- value head ----
    {
        float4 wv4 = *(const float4*)(wv + j0);
        float vs[4];
        #pragma unroll
        for (int p = 0; p < 4; p++)
            vs[p] = s_own[p][0]*wv4.x + s_own[p][1]*wv4.y + s_own[p][2]*wv4.z + s_own[p][3]*wv4.w;
        __syncthreads();   // layer-3 mm_g(wh) readers of Db done
        *(float4*)(Db + jg*32 + p0) = make_float4(vs[0], vs[1], vs[2], vs[3]);
        __syncthreads();
        if (t < TM){
            float v = bv[0];
            for (int j2 = 0; j2 < 32; j2++) v += Db[j2*32 + t];
            if (type == 0) val1[P0 + t] = v;
            else if (type == 2) val2[P0 + t - NN - MCN*NN] = v;
        }
        __syncthreads();
    }
    if (type == 2) return;

    // ---- backward ----
    float ds[4][4];
    {
        float4 wv4 = *(const float4*)(wv + j0);
        #pragma unroll
        for (int p = 0; p < 4; p++){ ds[p][0]=wv4.x; ds[p][1]=wv4.y; ds[p][2]=wv4.z; ds[p][3]=wv4.w; }
    }
    float proj[4] = {0.f, 0.f, 0.f, 0.f};
    float dxp[3] = {0.f, 0.f, 0.f};
    const int pi = t >> 3, il = t & 7;

    const float* WTz = WT;
    const float* WTg = WT + 16384;
    const float* WTr = WT + 2*16384;
    const float* WTh = WT + 3*16384;

#define DX_DOT(UMAT) \
    { _Pragma("unroll") for (int ii = 0; ii < 3; ii++){ \
        int i = il + 8*ii; \
        if (i < DD){ \
            const float* Urow = UMAT + i*UNITS; \
            float a = 0.f; \
            for (int j2 = 0; j2 < UNITS; j2++) a = fmaf(Db[offs(j2, pi)], Urow[j2], a); \
            dxp[ii] += a; \
        } } }

#define PROJ_FOLD(UMAT, SEL) \
    { float uv[4][4]; \
      ELT44(uv[p][jj] = 0.f) \
      mm_g(UMAT, DIMN, Vb, uv, jg, p0); \
      ELT44(proj[p] += uv[p][jj]*SEL[p][jj]) }

// MODE 0: gates live in zt/gt/rt/ht; MODE 1: recompute; MODE 2: load from global stash
#define BWD_LAYER(SLP, SINP, MODE) \
    { \
    float sl[4][4]; \
    read_own(SLP, sl, j0, p0); \
    if (MODE == 1){ GATES(SINP, sl) } \
    else if (MODE == 2){ \
        read_own(gb,         zt, j0, p0); \
        read_own(gb + 4096,  gt, j0, p0); \
        read_own(gb + 8192,  rt, j0, p0); \
        read_own(gb + 12288, ht, j0, p0); \
    } \
    float dhp[4][4], dzp[4][4], dgp[4][4], dsn[4][4]; \
    ELT44(float d=ds[p][jj]; float g=gt[p][jj]; float h=ht[p][jj]; float z=zt[p][jj]; float s=sl[p][jj]; \
        dhp[p][jj] = d*(1.f - g)*(1.f - h*h); \
        dgp[p][jj] = -d*h*(1.f - g*g); \
        dzp[p][jj] = d*s*(1.f - z*z); \
        dsn[p][jj] = d*z) \
    if (type == 1){ \
        PROJ_FOLD(uh, dhp) \
        PROJ_FOLD(uz, dzp) \
        PROJ_FOLD(ug, dgp) \
    } \
    __syncthreads(); write_own(Db, dhp, j0, p0); __syncthreads(); \
    if (type == 0){ DX_DOT(uh) } \
    float dsr[4][4]; \
    ELT44(dsr[p][jj] = 0.f) \
    mm_g(WTh, UNITS, Db, dsr, jg, p0); \
    float drp[4][4]; \
    ELT44(float dr=dsr[p][jj]; float r=rt[p][jj]; float s=sl[p][jj]; \
        drp[p][jj] = dr*s*(1.f - r*r); \
        dsn[p][jj] += dr*r) \
    if (type == 1){ PROJ_FOLD(ur, drp) } \
    __syncthreads(); write_own(Db, dzp, j0, p0); __syncthreads(); \
    if (type == 0){ DX_DOT(uz) } \
    mm_g(WTz, UNITS, Db, dsn, jg, p0); \
    __syncthreads(); write_own(Db, dgp, j0, p0); __syncthreads(); \
    if (type == 0){ DX_DOT(ug) } \
    mm_g(WTg, UNITS, Db, dsn, jg, p0); \
    __syncthreads(); write_own(Db, drp, j0, p0); __syncthreads(); \
    if (type == 0){ DX_DOT(ur) } \
    mm_g(WTr, UNITS, Db, dsn, jg, p0); \
    ELT44(ds[p][jj] = dsn[p][jj]) \
    }

    BWD_LAYER(S2, S2, 0)               // layer 3: gates live from FWD_LAYER(S2)
    BWD_LAYER(S1, S1, (SG ? 2 : 1))    // layer 2: stashed gates (or recompute)
    BWD_LAYER(S0, S0, 1)               // layer 1: recompute

    // first layer backward + epilogue
    {
        float s0l[4][4];
        read_own(S0, s0l, j0, p0);
        float v0[4][4];
        ELT44(v0[p][jj] = ds[p][jj]*(1.f - s0l[p][jj]*s0l[p][jj]))

        if (type == 1){
            PROJ_FOLD(w1, v0)
            __syncthreads();   // mm_g(WTr) readers of Db done
            *(float4*)(Db + jg*32 + p0) = make_float4(proj[0], proj[1], proj[2], proj[3]);
            __syncthreads();
            if (t < TM){
                float s = 0.f;
                for (int j2 = 0; j2 < 32; j2++) s += Db[j2*32 + t];
                atomicAdd(t12acc + base_n + t, s);
            }
        } else {
            __syncthreads(); write_own(Db, v0, j0, p0); __syncthreads();
            DX_DOT(w1)
            #pragma unroll
            for (int ii = 0; ii < 3; ii++){
                int i = il + 8*ii;
                if (i < DD) fp1[(P0 + pi)*DD + i] = dxp[ii];
            }
        }
    }
}

__global__ __launch_bounds__(256, 2) void dgm_sg(DGM_PARAMS){
    __shared__ float lds[L_TOT];
    dgm_body<1>(lds, DGM_ARGS);
}
__global__ __launch_bounds__(256, 2) void dgm_rc(DGM_PARAMS){
    __shared__ float lds[L_TOT];
    dgm_body<0>(lds, DGM_ARGS);
}

__global__ void finalize_k(const float* __restrict__ inputs, const float* __restrict__ eps,
    const float* __restrict__ Lm, const float* __restrict__ fp1, const float* __restrict__ val1,
    const float* __restrict__ val2, const float* __restrict__ t12acc, float* __restrict__ out)
{
    int n = blockIdx.x*256 + threadIdx.x;
    if (n >= NN) return;
    float fp[DD];
    #pragma unroll
    for (int k = 0; k < DD; k++) fp[k] = fp1[n*DD + k];
    float t11 = fp[DIMN];
    #pragma unroll
    for (int k = 0; k < DIMN; k++) t11 = fmaf(MUC*inputs[n*DD + k], fp[k], t11);
    float esum[DIMN];
    #pragma unroll
    for (int d = 0; d < DIMN; d++){
        float a = 0.f;
        for (int m = 0; m < MCN; m++) a += eps[(size_t)(m*NN + n)*DIMN + d];
        esum[d] = a;
    }
    float t12b = 0.f;
    #pragma unroll
    for (int k = 0; k < DIMN; k++){
        float loc = inputs[n*DD + k];
        float ssum = (float)MCN * loc;
        #pragma unroll
        for (int d = 0; d < DIMN; d++) ssum = fmaf(esum[d], Lm[k*DIMN + d], ssum);
        float vsum = ssum * (SIGC*loc);
        t12b = fmaf(fp[k], vsum, t12b);
    }
    float term12 = (t12acc[n] - t12b) * (1.0f/(DELTAC*(float)MCN));
    out[n] = t11 + 0.5f*term12 - RC*val1[n];

    float prod = 1.f;
    #pragma unroll
    for (int k = 0; k < DIMN; k++) prod *= inputs[(NN + n)*DD + k];
    float payoff = powf(prod, 1.0f/(float)DIMN);
    if (!(payoff > 0.f)) payoff = 0.f;
    out[NN + n] = val2[n] - payoff;
}

extern "C" void kernel_launch(void* const* d_in, const int* in_sizes, int n_in,
                              void* d_out, int out_size, void* d_ws, size_t ws_size,
                              hipStream_t stream)
{
    const float* inputs = (const float*)d_in[0];
    const float* eps    = (const float*)d_in[1];
    const float* w1     = (const float*)d_in[2];
    const float* b1     = (const float*)d_in[3];
    const float* uz     = (const float*)d_in[4];
    const float* wz     = (const float*)d_in[5];
    const float* bz     = (const float*)d_in[6];
    const float* ug     = (const float*)d_in[7];
    const float* wg     = (const float*)d_in[8];
    const float* bg     = (const float*)d_in[9];
    const float* urr    = (const float*)d_in[10];
    const float* wr     = (const float*)d_in[11];
    const float* br     = (const float*)d_in[12];
    const float* uh     = (const float*)d_in[13];
    const float* wh     = (const float*)d_in[14];
    const float* bh     = (const float*)d_in[15];
    const float* wv     = (const float*)d_in[16];
    const float* bv     = (const float*)d_in[17];

    float* ws    = (float*)d_ws;
    float* Lm    = ws + OFF_L;
    float* WT    = ws + OFF_WT;
    float* U4    = ws + OFF_U4;
    float* W3    = ws + OFF_W3;
    float* fp1   = ws + OFF_FP1;
    float* val1  = ws + OFF_VAL1;
    float* val2  = ws + OFF_VAL2;
    float* t12   = ws + OFF_T12;
    float* gates = ws + OFF_GATES;
    float* out   = (float*)d_out;

    hipMemsetAsync(t12, 0, NN*sizeof(float), stream);
    hipLaunchKernelGGL(chol_kernel, dim3(1), dim3(64), 0, stream, Lm);
    hipLaunchKernelGGL(transpose_k, dim3(256), dim3(256), 0, stream, wz, wg, wr, wh, WT);
    hipLaunchKernelGGL(pack_u4w3, dim3(234), dim3(256), 0, stream, uz, ug, urr, uh, wz, wg, wr, U4, W3);

    size_t need_bytes = ((size_t)OFF_GATES + (size_t)NBLK * (size_t)GB_STRIDE) * sizeof(float);
    if (ws_size >= need_bytes){
        hipLaunchKernelGGL(dgm_sg, dim3(NBLK), dim3(256), 0, stream,
            inputs, eps, w1, b1, uz, bz, ug, bg, urr, br, uh, wh, bh, wv, bv,
            Lm, WT, U4, W3, gates, fp1, val1, val2, t12);
    } else {
        hipLaunchKernelGGL(dgm_rc, dim3(NBLK), dim3(256), 0, stream,
            inputs, eps, w1, b1, uz, bz, ug, bg, urr, br, uh, wh, bh, wv, bv,
            Lm, WT, U4, W3, gates, fp1, val1, val2, t12);
    }
    hipLaunchKernelGGL(finalize_k, dim3(8), dim3(256), 0, stream,
        inputs, eps, Lm, fp1, val1, val2, t12, out);
}